// Round 1
// baseline (717.603 us; speedup 1.0000x reference)
//
#include <hip/hip_runtime.h>

#define VOCAB 10000
#define HIDDEN 256
#define BATCH 32
#define SEQ 256
#define NPAD 10112            // 79 * 128
#define NTILES 79
#define MTILES 64             // 8192 / 128
#define TOTAL_TILES 5056      // MTILES * NTILES
#define CHUNK 4               // tiles per dispenser grab (same mt -> A-tile L2 reuse)
#define NCHUNKS 1264          // TOTAL_TILES / CHUNK (exact)
#define LOGITS_ELEMS 81920000LL
#define GRID_BLOCKS 256

typedef __attribute__((ext_vector_type(8))) short short8;
typedef __attribute__((ext_vector_type(4))) float f32x4;

static __device__ __forceinline__ unsigned short f32_to_bf16(float f) {
    unsigned u = __float_as_uint(f);
    u += 0x7fffu + ((u >> 16) & 1u);   // round-to-nearest-even
    return (unsigned short)(u >> 16);
}

// ---------------------------------------------------------------------------
// Kernel 1: W_ihT[v][h] = W_ih[h][v] via 64x64 LDS tile, coalesced both ways.
// Block 0 additionally zeroes the producer/consumer sync words (prog[32]+disp)
// so each graph replay starts from a clean state (same-stream ordering makes
// this visible to the fused kernel).
// ---------------------------------------------------------------------------
__global__ __launch_bounds__(256) void transpose_wih(const float* __restrict__ W_ih,
                                                     float* __restrict__ W_ihT,
                                                     int* __restrict__ sync_ws) {
    __shared__ float tile[64][65];          // +1 pad: conflict-free transpose read
    if (blockIdx.x == 0 && threadIdx.x < 33) sync_ws[threadIdx.x] = 0;
    const int v0   = (blockIdx.x >> 2) * 64;
    const int h0   = (blockIdx.x & 3) * 64;
    const int lane = threadIdx.x & 63;
    const int wv   = threadIdx.x >> 6;      // 0..3

#pragma unroll
    for (int i = 0; i < 16; ++i) {
        const int row = i * 4 + wv;
        const int v   = v0 + lane;
        if (v < VOCAB)
            tile[row][lane] = W_ih[(long)(h0 + row) * VOCAB + v];
    }
    __syncthreads();
#pragma unroll
    for (int i = 0; i < 16; ++i) {
        const int vrow = i * 4 + wv;
        const int v    = v0 + vrow;
        if (v < VOCAB)
            W_ihT[(long)v * HIDDEN + h0 + lane] = tile[lane][vrow];
    }
}

// ---------------------------------------------------------------------------
// Kernel 2: Wb = bf16(W_out) padded with zero rows to NPAD — one block per row
// ---------------------------------------------------------------------------
__global__ __launch_bounds__(256) void prep_wout(const float* __restrict__ W_out,
                                                 unsigned short* __restrict__ Wb) {
    const int n = blockIdx.x;        // 0..10111
    const int k = threadIdx.x;
    float v = (n < VOCAB) ? W_out[(long)n * HIDDEN + k] : 0.f;
    Wb[(long)n * HIDDEN + k] = f32_to_bf16(v);
}

// ---------------------------------------------------------------------------
// Kernel 3: FUSED scan (producer) + logits GEMM (persistent consumers).
// Cooperative launch, grid = 256 blocks x 512 threads, 1 block/CU (LDS pad
// forces occupancy 1 so scan blocks never share a CU with a consumer).
//
//  - blocks 0..31: the proven scan body (identical math to the 639us version);
//    after step s with s%4==3, agent-release publish prog[b]=s+1.  Then the
//    block joins the consumer pool.
//  - consumers: grab CHUNK=4 consecutive tiles from an atomic dispenser
//    (consecutive tiles share mt -> steps 4mt..4mt+3 -> A-tile reuse), wait
//    until all 32 batches have prog >= 4*mt_last+4, agent-acquire fence
//    (buffer_inv: required for cross-XCD visibility + cross-replay staleness),
//    then run a 128x128, BK=64 MFMA tile:
//      * double-buffered LDS, stage(kb+1) issued BEFORE compute(kb)  [T3-min]
//      * T2 XOR swizzle: global SOURCE pre-swizzled (chunk k8 ^= row&7) with a
//        LINEAR global_load_lds dest (rule 21), reads apply the same XOR ->
//        the old 16-way stride-128B fragment conflict becomes 2-way (free).
//      * C stores nontemporal: C is write-once/never-read; keeps L2 clean so
//        the producers' release-writebacks stay cheap.
// Deadlock-free: producers never wait on consumers; cooperative launch
// guarantees all 256 blocks co-resident.
// ---------------------------------------------------------------------------
__global__ __launch_bounds__(512, 2) void fused_kernel(
        const int*   __restrict__ inputs,   // (32, 256)
        const float* __restrict__ state,    // (1, 32, 256)
        const float* __restrict__ W_hh,     // (256, 256)
        const float* __restrict__ b_ih,
        const float* __restrict__ b_hh,
        const float* __restrict__ W_ihT,    // (10000, 256)
        unsigned short* __restrict__ Ybf,   // (8192, 256) bf16
        float* __restrict__ hout,           // (32, 256)
        const unsigned short* __restrict__ Wb,  // (10112, 256) bf16
        const float* __restrict__ b_out,        // (10000,)
        float* __restrict__ C,                  // (8192, 10000) f32
        int* __restrict__ prog,             // [32] per-batch published step count
        int* __restrict__ disp)             // [1] chunk dispenser
{
    __shared__ float hbuf[HIDDEN];
    __shared__ float psum[4 * HIDDEN];
    __shared__ __align__(16) unsigned short lA[2][128 * 64];
    __shared__ __align__(16) unsigned short lB[2][128 * 64];
    __shared__ int sh_g;
    __shared__ char occ_pad[16384];   // bump LDS to ~87KB -> exactly 1 block/CU

    const int t = threadIdx.x;
    if (disp == nullptr) occ_pad[0] = 1;   // never true; keeps occ_pad allocated

    if (blockIdx.x < BATCH) {
        // ------------------------- producer: RNN scan -------------------------
        const int b  = blockIdx.x;
        const int jj = t & 63;
        const int q  = (t >> 6) & 3;
        const int h2 = t >> 8;

        float w[2][64];
#pragma unroll
        for (int r = 0; r < 2; ++r) {
            const float* src = W_hh + (jj + 64 * (2 * h2 + r)) * HIDDEN + 64 * q;
#pragma unroll
            for (int k4 = 0; k4 < 16; ++k4) {
                const float4 v = *(const float4*)(src + 4 * k4);
                w[r][4 * k4 + 0] = v.x;
                w[r][4 * k4 + 1] = v.y;
                w[r][4 * k4 + 2] = v.z;
                w[r][4 * k4 + 3] = v.w;
            }
        }

        float biasv = 0.f, xcur = 0.f;
        if (t < HIDDEN) {
            biasv   = b_ih[t] + b_hh[t];
            hbuf[t] = state[b * HIDDEN + t];
            const int tok0 = inputs[b * SEQ];
            xcur = W_ihT[(long)tok0 * HIDDEN + t];
        }
        __syncthreads();

        for (int step = 0; step < SEQ; ++step) {
            float xnext = 0.f;
            if (t < HIDDEN && step + 1 < SEQ) {
                const int tokn = inputs[b * SEQ + step + 1];
                xnext = W_ihT[(long)tokn * HIDDEN + t];
            }

            float a00 = 0.f, a01 = 0.f, a10 = 0.f, a11 = 0.f;
#pragma unroll
            for (int k4 = 0; k4 < 8; ++k4) {
                const float4 hv = *(const float4*)&hbuf[64 * q + 4 * k4];  // broadcast
                a00 = fmaf(w[0][4 * k4 + 0], hv.x, a00);
                a00 = fmaf(w[0][4 * k4 + 1], hv.y, a00);
                a00 = fmaf(w[0][4 * k4 + 2], hv.z, a00);
                a00 = fmaf(w[0][4 * k4 + 3], hv.w, a00);
                a10 = fmaf(w[1][4 * k4 + 0], hv.x, a10);
                a10 = fmaf(w[1][4 * k4 + 1], hv.y, a10);
                a10 = fmaf(w[1][4 * k4 + 2], hv.z, a10);
                a10 = fmaf(w[1][4 * k4 + 3], hv.w, a10);
            }
#pragma unroll
            for (int k4 = 8; k4 < 16; ++k4) {
                const float4 hv = *(const float4*)&hbuf[64 * q + 4 * k4];
                a01 = fmaf(w[0][4 * k4 + 0], hv.x, a01);
                a01 = fmaf(w[0][4 * k4 + 1], hv.y, a01);
                a01 = fmaf(w[0][4 * k4 + 2], hv.z, a01);
                a01 = fmaf(w[0][4 * k4 + 3], hv.w, a01);
                a11 = fmaf(w[1][4 * k4 + 0], hv.x, a11);
                a11 = fmaf(w[1][4 * k4 + 1], hv.y, a11);
                a11 = fmaf(w[1][4 * k4 + 2], hv.z, a11);
                a11 = fmaf(w[1][4 * k4 + 3], hv.w, a11);
            }
            psum[q * HIDDEN + jj + 64 * (2 * h2 + 0)] = a00 + a01;
            psum[q * HIDDEN + jj + 64 * (2 * h2 + 1)] = a10 + a11;
            __syncthreads();

            if (t < HIDDEN) {   // wave-uniform branch (waves 0-3)
                const float s = psum[t] + psum[HIDDEN + t]
                              + psum[2 * HIDDEN + t] + psum[3 * HIDDEN + t];
                const float hnew = tanhf(s + xcur + biasv);
                hbuf[t] = hnew;
                Ybf[((long)step * BATCH + b) * HIDDEN + t] = f32_to_bf16(hnew);
                xcur = xnext;
            }
            __syncthreads();   // drains vmcnt per thread -> Ybf stores are in L2

            if (((step & 3) == 3) && t == 0) {
                // agent release: buffer_wbl2 flushes this XCD's L2 (cheap: C is
                // nontemporal so only ~4KB of Ybf is dirty), then publish.
                __builtin_amdgcn_fence(__ATOMIC_RELEASE, "agent");
                __hip_atomic_store(&prog[b], step + 1, __ATOMIC_RELAXED,
                                   __HIP_MEMORY_SCOPE_AGENT);
            }
        }
        if (t < HIDDEN) hout[b * HIDDEN + t] = hbuf[t];
        __syncthreads();
        // fall through: this block becomes a consumer
    }

    // ------------------------- consumer: persistent GEMM -------------------------
    const int lane = t & 63;
    const int wave = t >> 6;            // 0..7
    const int wm   = (wave & 1) * 64;   // 64x32 quadrant per wave
    const int wn   = (wave >> 1) * 32;
    const int l15  = lane & 15;
    const int quad = lane >> 4;
    const f32x4 zero = {0.f, 0.f, 0.f, 0.f};

    for (;;) {
        if (t == 0) sh_g = atomicAdd(disp, 1);
        __syncthreads();                 // publishes sh_g; also separates LDS reuse
        const int chunk = sh_g;          // uniform
        if (chunk >= NCHUNKS) break;

        const int g0   = chunk * CHUNK;
        const int need = 4 * ((g0 + CHUNK - 1) / NTILES) + 4;   // steps required
        if (t == 0) {
            for (;;) {
                bool ok = true;
                for (int bb = 0; bb < BATCH; ++bb)
                    ok &= (__hip_atomic_load(&prog[bb], __ATOMIC_RELAXED,
                                             __HIP_MEMORY_SCOPE_AGENT) >= need);
                if (ok) break;
                __builtin_amdgcn_s_sleep(8);
            }
            // agent acquire: buffer_inv -> this CU/XCD will re-fetch fresh Ybf
            __builtin_amdgcn_fence(__ATOMIC_ACQUIRE, "agent");
        }
        __syncthreads();   // orders the fence before every thread's loads

        for (int g = g0; g < g0 + CHUNK; ++g) {
            const int mt = g / NTILES;
            const int nt = g - mt * NTILES;
            const long m0 = (long)mt * 128;
            const long n0 = (long)nt * 128;

            f32x4 acc[4][2];
#pragma unroll
            for (int i = 0; i < 4; ++i)
#pragma unroll
                for (int j = 0; j < 2; ++j)
                    acc[i][j] = zero;

            // stage kb into buf: LINEAR LDS dest (wave-uniform base + lane*16),
            // global source chunk pre-swizzled by row&7 (rule 21 / m201 pattern)
            auto stage = [&](int kb, int buf) {
#pragma unroll
                for (int it = 0; it < 2; ++it) {
                    const int c   = it * 512 + t;    // 0..1023 (=128 rows x 8 chunks)
                    const int row = c >> 3;
                    const int sk8 = (c & 7) ^ (row & 7);
                    const unsigned short* ga = Ybf + (m0 + row) * HIDDEN + kb * 64 + sk8 * 8;
                    const unsigned short* gb = Wb  + (n0 + row) * HIDDEN + kb * 64 + sk8 * 8;
                    __builtin_amdgcn_global_load_lds(
                        (const __attribute__((address_space(1))) void*)ga,
                        (__attribute__((address_space(3))) void*)(&lA[buf][c * 8]), 16, 0, 0);
                    __builtin_amdgcn_global_load_lds(
                        (const __attribute__((address_space(1))) void*)gb,
                        (__attribute__((address_space(3))) void*)(&lB[buf][c * 8]), 16, 0, 0);
                }
            };

            stage(0, 0);
            __syncthreads();             // drains stage(0) (vmcnt0 in barrier)
#pragma unroll
            for (int kb = 0; kb < 4; ++kb) {
                if (kb < 3) stage(kb + 1, (kb + 1) & 1);   // overlap with compute
                const unsigned short* bufA = lA[kb & 1];
                const unsigned short* bufB = lB[kb & 1];
#pragma unroll
                for (int ki = 0; ki < 2; ++ki) {
                    short8 af[4], bfr[2];
#pragma unroll
                    for (int i = 0; i < 4; ++i) {
                        const int r = wm + 16 * i + l15;
                        af[i] = *(const short8*)
                            &bufA[r * 64 + (((ki * 4 + quad) ^ (r & 7)) * 8)];
                    }
#pragma unroll
                    for (int j = 0; j < 2; ++j) {
                        const int r = wn + 16 * j + l15;
                        bfr[j] = *(const short8*)
                            &bufB[r * 64 + (((ki * 4 + quad) ^ (r & 7)) * 8)];
                    }
#pragma unroll
                    for (int i = 0; i < 4; ++i)
#pragma unroll
                        for (int j = 0; j < 2; ++j)
                            acc[i][j] = __builtin_amdgcn_mfma_f32_16x16x32_bf16(
                                af[i], bfr[j], acc[i][j], 0, 0, 0);
                }
                if (kb < 3) __syncthreads();
            }

            // epilogue: C/D layout col = lane&15, row = quad*4 + reg.
            // Nontemporal: C is never re-read; keep it out of L2.
#pragma unroll
            for (int j = 0; j < 2; ++j) {
                const long col = n0 + wn + 16 * j + l15;
                if (col < VOCAB) {
                    const float bv = b_out[col];
#pragma unroll
                    for (int i = 0; i < 4; ++i) {
                        const long row = m0 + wm + 16 * i + quad * 4;
                        float* Cp = C + row * VOCAB + col;
#pragma unroll
                        for (int r = 0; r < 4; ++r)
                            __builtin_nontemporal_store(acc[i][j][r] + bv,
                                                        Cp + (long)r * VOCAB);
                    }
                }
            }
            // no barrier needed: next tile's stage(0,0) hits buf0, whose last
            // readers finished before the kb=2 barrier of this tile.
        }
    }
}

// ---------------------------------------------------------------------------
extern "C" void kernel_launch(void* const* d_in, const int* in_sizes, int n_in,
                              void* d_out, int out_size, void* d_ws, size_t ws_size,
                              hipStream_t stream) {
    const int*   inputs = (const int*)  d_in[0];
    const float* state  = (const float*)d_in[1];
    const float* W_ih   = (const float*)d_in[2];
    const float* b_ih   = (const float*)d_in[3];
    const float* W_hh   = (const float*)d_in[4];
    const float* b_hh   = (const float*)d_in[5];
    const float* W_out  = (const float*)d_in[6];
    const float* b_out  = (const float*)d_in[7];
    float* out = (float*)d_out;

    char* ws = (char*)d_ws;
    float*          W_ihT = (float*)ws;                        // 10,240,000 B
    unsigned short* Wb    = (unsigned short*)(ws + 10240000);  //  5,177,344 B
    unsigned short* Ybf   = (unsigned short*)(ws + 15417344);  //  4,194,304 B
    int*            prog  = (int*)(ws + 19611648);             //  32 ints
    int*            disp  = prog + 32;                         //  1 int
    float*          hout  = out + LOGITS_ELEMS;

    transpose_wih<<<157 * 4, 256, 0, stream>>>(W_ih, W_ihT, prog);
    prep_wout<<<NPAD, 256, 0, stream>>>(W_out, Wb);

    void* args[13];
    args[0]  = (void*)&inputs;
    args[1]  = (void*)&state;
    args[2]  = (void*)&W_hh;
    args[3]  = (void*)&b_ih;
    args[4]  = (void*)&b_hh;
    args[5]  = (void*)&W_ihT;
    args[6]  = (void*)&Ybf;
    args[7]  = (void*)&hout;
    args[8]  = (void*)&Wb;
    args[9]  = (void*)&b_out;
    args[10] = (void*)&out;
    args[11] = (void*)&prog;
    args[12] = (void*)&disp;
    hipLaunchCooperativeKernel((void*)fused_kernel, dim3(GRID_BLOCKS), dim3(512),
                               args, 0, stream);
}

// Round 2
// 603.473 us; speedup vs baseline: 1.1891x; 1.1891x over previous
//
#include <hip/hip_runtime.h>

#define VOCAB 10000
#define HIDDEN 256
#define BATCH 32
#define SEQ 256
#define NPAD 10112            // 79 * 128
#define NTILES 79
#define MTILES 64             // 8192 / 128
#define LOGITS_ELEMS 81920000LL

typedef __attribute__((ext_vector_type(8))) short short8;
typedef __attribute__((ext_vector_type(4))) float f32x4;

static __device__ __forceinline__ unsigned short f32_to_bf16(float f) {
    unsigned u = __float_as_uint(f);
    u += 0x7fffu + ((u >> 16) & 1u);   // round-to-nearest-even
    return (unsigned short)(u >> 16);
}

// ---------------------------------------------------------------------------
// Kernel 1: W_ihT[v][h] = W_ih[h][v] via 64x64 LDS tile, coalesced both ways.
// ---------------------------------------------------------------------------
__global__ __launch_bounds__(256) void transpose_wih(const float* __restrict__ W_ih,
                                                     float* __restrict__ W_ihT) {
    __shared__ float tile[64][65];          // +1 pad: conflict-free transpose read
    const int v0   = (blockIdx.x >> 2) * 64;
    const int h0   = (blockIdx.x & 3) * 64;
    const int lane = threadIdx.x & 63;
    const int wv   = threadIdx.x >> 6;      // 0..3

#pragma unroll
    for (int i = 0; i < 16; ++i) {
        const int row = i * 4 + wv;         // h offset within tile
        const int v   = v0 + lane;
        if (v < VOCAB)
            tile[row][lane] = W_ih[(long)(h0 + row) * VOCAB + v];
    }
    __syncthreads();
#pragma unroll
    for (int i = 0; i < 16; ++i) {
        const int vrow = i * 4 + wv;        // v offset within tile
        const int v    = v0 + vrow;
        if (v < VOCAB)
            W_ihT[(long)v * HIDDEN + h0 + lane] = tile[lane][vrow];
    }
}

// ---------------------------------------------------------------------------
// Kernel 2: Wb = bf16(W_out) padded with zero rows to NPAD — one block per row
// ---------------------------------------------------------------------------
__global__ __launch_bounds__(256) void prep_wout(const float* __restrict__ W_out,
                                                 unsigned short* __restrict__ Wb) {
    const int n = blockIdx.x;        // 0..10111
    const int k = threadIdx.x;
    float v = (n < VOCAB) ? W_out[(long)n * HIDDEN + k] : 0.f;
    Wb[(long)n * HIDDEN + k] = f32_to_bf16(v);
}

// ---------------------------------------------------------------------------
// Kernel 3: RNN scan — EXACT round-0 body (register-resident W_hh: 128 f32 per
// thread, proven to fit the 256-VGPR cap standalone; round 1 showed that any
// co-compiled consumer code makes the allocator spill this to scratch, which
// cost ~250us — so this kernel stays alone).
// One block (512 thr, 8 waves) per batch row.
// ---------------------------------------------------------------------------
__global__ __launch_bounds__(512, 2) void scan_kernel(
        const int*   __restrict__ inputs,   // (32, 256)
        const float* __restrict__ state,    // (1, 32, 256)
        const float* __restrict__ W_hh,     // (256, 256)
        const float* __restrict__ b_ih,
        const float* __restrict__ b_hh,
        const float* __restrict__ W_ihT,    // (10000, 256)
        unsigned short* __restrict__ Ybf,   // (8192, 256) bf16
        float* __restrict__ hout)           // (32, 256)
{
    __shared__ float hbuf[HIDDEN];
    __shared__ float psum[4 * HIDDEN];

    const int b  = blockIdx.x;
    const int t  = threadIdx.x;
    const int jj = t & 63;
    const int q  = (t >> 6) & 3;
    const int h2 = t >> 8;

    float w[2][64];
#pragma unroll
    for (int r = 0; r < 2; ++r) {
        const float* src = W_hh + (jj + 64 * (2 * h2 + r)) * HIDDEN + 64 * q;
#pragma unroll
        for (int k4 = 0; k4 < 16; ++k4) {
            const float4 v = *(const float4*)(src + 4 * k4);
            w[r][4 * k4 + 0] = v.x;
            w[r][4 * k4 + 1] = v.y;
            w[r][4 * k4 + 2] = v.z;
            w[r][4 * k4 + 3] = v.w;
        }
    }

    float biasv = 0.f, xcur = 0.f;
    if (t < HIDDEN) {
        biasv   = b_ih[t] + b_hh[t];
        hbuf[t] = state[b * HIDDEN + t];
        const int tok0 = inputs[b * SEQ];
        xcur = W_ihT[(long)tok0 * HIDDEN + t];
    }
    __syncthreads();

    for (int step = 0; step < SEQ; ++step) {
        float xnext = 0.f;
        if (t < HIDDEN && step + 1 < SEQ) {
            const int tokn = inputs[b * SEQ + step + 1];
            xnext = W_ihT[(long)tokn * HIDDEN + t];
        }

        // 4 independent FMA chains: 2 rows x 2 k-halves
        float a00 = 0.f, a01 = 0.f, a10 = 0.f, a11 = 0.f;
#pragma unroll
        for (int k4 = 0; k4 < 8; ++k4) {
            const float4 hv = *(const float4*)&hbuf[64 * q + 4 * k4];  // broadcast
            a00 = fmaf(w[0][4 * k4 + 0], hv.x, a00);
            a00 = fmaf(w[0][4 * k4 + 1], hv.y, a00);
            a00 = fmaf(w[0][4 * k4 + 2], hv.z, a00);
            a00 = fmaf(w[0][4 * k4 + 3], hv.w, a00);
            a10 = fmaf(w[1][4 * k4 + 0], hv.x, a10);
            a10 = fmaf(w[1][4 * k4 + 1], hv.y, a10);
            a10 = fmaf(w[1][4 * k4 + 2], hv.z, a10);
            a10 = fmaf(w[1][4 * k4 + 3], hv.w, a10);
        }
#pragma unroll
        for (int k4 = 8; k4 < 16; ++k4) {
            const float4 hv = *(const float4*)&hbuf[64 * q + 4 * k4];
            a01 = fmaf(w[0][4 * k4 + 0], hv.x, a01);
            a01 = fmaf(w[0][4 * k4 + 1], hv.y, a01);
            a01 = fmaf(w[0][4 * k4 + 2], hv.z, a01);
            a01 = fmaf(w[0][4 * k4 + 3], hv.w, a01);
            a11 = fmaf(w[1][4 * k4 + 0], hv.x, a11);
            a11 = fmaf(w[1][4 * k4 + 1], hv.y, a11);
            a11 = fmaf(w[1][4 * k4 + 2], hv.z, a11);
            a11 = fmaf(w[1][4 * k4 + 3], hv.w, a11);
        }
        psum[q * HIDDEN + jj + 64 * (2 * h2 + 0)] = a00 + a01;  // stride-1 per wave
        psum[q * HIDDEN + jj + 64 * (2 * h2 + 1)] = a10 + a11;
        __syncthreads();

        if (t < HIDDEN) {   // wave-uniform branch (waves 0-3)
            const float s = psum[t] + psum[HIDDEN + t]
                          + psum[2 * HIDDEN + t] + psum[3 * HIDDEN + t];
            const float hnew = tanhf(s + xcur + biasv);
            hbuf[t] = hnew;
            Ybf[((long)step * BATCH + b) * HIDDEN + t] = f32_to_bf16(hnew);
            xcur = xnext;
        }
        __syncthreads();
    }

    if (t < HIDDEN) hout[b * HIDDEN + t] = hbuf[t];
}

// ---------------------------------------------------------------------------
// Kernel 4: logits = Y(bf16) @ Wb^T + b_out.  128x128 tile, BK=64, 4 waves,
// 4x4 16x16x32-bf16 frags per wave.  vs the 639us version:
//   * T2 XOR swizzle (pre-swizzled global SOURCE, linear global_load_lds dest,
//     same XOR on ds_read — rule 21 / m201 pattern; verified correct in the
//     round-1 consumer).  Old fragment reads were 16-way bank conflicts
//     (stride 128B rows); now (r&7)-XOR -> 2-way = free.
//   * double-buffered LDS, stage(kb+1) issued BEFORE compute(kb): one
//     vmcnt-drain barrier per K-step (T3-minimum 2-phase).
//   * nontemporal C stores: C is write-once/never-read -> keep L2 clean.
// Expected regime: C-write-bound (~327.7MB / 6.3TB/s = 52us floor).
// ---------------------------------------------------------------------------
__global__ __launch_bounds__(256) void gemm_kernel(
        const unsigned short* __restrict__ A,   // (8192, 256) bf16
        const unsigned short* __restrict__ B,   // (10112, 256) bf16
        const float* __restrict__ bias,         // (10000,)
        float* __restrict__ C)                  // (8192, 10000) f32
{
    __shared__ __align__(16) unsigned short lA[2][128 * 64];
    __shared__ __align__(16) unsigned short lB[2][128 * 64];

    const int t     = threadIdx.x;
    const int bid   = blockIdx.x;
    const int ntile = bid % NTILES;
    const int mtile = bid / NTILES;
    const long m0   = (long)mtile * 128;
    const long n0   = (long)ntile * 128;
    const int lane  = t & 63;
    const int wave  = t >> 6;
    const int wm    = (wave & 1) * 64;
    const int wn    = (wave >> 1) * 64;
    const int l15   = lane & 15;
    const int quad  = lane >> 4;

    const f32x4 zero = {0.f, 0.f, 0.f, 0.f};
    f32x4 acc[4][4];
#pragma unroll
    for (int i = 0; i < 4; ++i)
#pragma unroll
        for (int j = 0; j < 4; ++j)
            acc[i][j] = zero;

    // stage kb into buf: LINEAR LDS dest (wave-uniform base + lane*16 order),
    // global source chunk pre-swizzled by row&7.
    auto stage = [&](int kb, int buf) {
#pragma unroll
        for (int it = 0; it < 4; ++it) {
            const int c   = it * 256 + t;    // 0..1023 = 128 rows x 8 chunks
            const int row = c >> 3;
            const int sk8 = (c & 7) ^ (row & 7);
            const unsigned short* ga = A + (m0 + row) * HIDDEN + kb * 64 + sk8 * 8;
            const unsigned short* gb = B + (n0 + row) * HIDDEN + kb * 64 + sk8 * 8;
            __builtin_amdgcn_global_load_lds(
                (const __attribute__((address_space(1))) void*)ga,
                (__attribute__((address_space(3))) void*)(&lA[buf][c * 8]), 16, 0, 0);
            __builtin_amdgcn_global_load_lds(
                (const __attribute__((address_space(1))) void*)gb,
                (__attribute__((address_space(3))) void*)(&lB[buf][c * 8]), 16, 0, 0);
        }
    };

    stage(0, 0);
    __syncthreads();                         // drains stage(0)

#pragma unroll
    for (int kb = 0; kb < 4; ++kb) {
        if (kb < 3) stage(kb + 1, (kb + 1) & 1);   // overlap loads with compute
        const unsigned short* bufA = lA[kb & 1];
        const unsigned short* bufB = lB[kb & 1];
#pragma unroll
        for (int ki = 0; ki < 2; ++ki) {
            short8 af[4], bf[4];
#pragma unroll
            for (int i = 0; i < 4; ++i) {
                const int ra = wm + 16 * i + l15;
                af[i] = *(const short8*)
                    &bufA[ra * 64 + (((ki * 4 + quad) ^ (ra & 7)) * 8)];
                const int rb = wn + 16 * i + l15;
                bf[i] = *(const short8*)
                    &bufB[rb * 64 + (((ki * 4 + quad) ^ (rb & 7)) * 8)];
            }
#pragma unroll
            for (int i = 0; i < 4; ++i)
#pragma unroll
                for (int j = 0; j < 4; ++j)
                    acc[i][j] = __builtin_amdgcn_mfma_f32_16x16x32_bf16(
                        af[i], bf[j], acc[i][j], 0, 0, 0);
        }
        if (kb < 3) __syncthreads();
        // barrier drains vmcnt -> buf[(kb+1)&1] ready; LDS reads of buf[kb&1]
        // complete -> safe for the next stage() to overwrite it.
    }

    // epilogue: C/D layout col = lane&15, row = quad*4 + reg.  Nontemporal:
    // C is never re-read; bypass L2.
#pragma unroll
    for (int j = 0; j < 4; ++j) {
        const long col = n0 + wn + 16 * j + l15;
        if (col < VOCAB) {
            const float bv = bias[col];
#pragma unroll
            for (int i = 0; i < 4; ++i) {
                const long row = m0 + wm + 16 * i + quad * 4;
                float* Cp = C + row * VOCAB + col;
#pragma unroll
                for (int r = 0; r < 4; ++r)
                    __builtin_nontemporal_store(acc[i][j][r] + bv,
                                                Cp + (long)r * VOCAB);
            }
        }
    }
}

// ---------------------------------------------------------------------------
extern "C" void kernel_launch(void* const* d_in, const int* in_sizes, int n_in,
                              void* d_out, int out_size, void* d_ws, size_t ws_size,
                              hipStream_t stream) {
    const int*   inputs = (const int*)  d_in[0];
    const float* state  = (const float*)d_in[1];
    const float* W_ih   = (const float*)d_in[2];
    const float* b_ih   = (const float*)d_in[3];
    const float* W_hh   = (const float*)d_in[4];
    const float* b_hh   = (const float*)d_in[5];
    const float* W_out  = (const float*)d_in[6];
    const float* b_out  = (const float*)d_in[7];
    float* out = (float*)d_out;

    char* ws = (char*)d_ws;
    float*          W_ihT = (float*)ws;                        // 10,240,000 B
    unsigned short* Wb    = (unsigned short*)(ws + 10240000);  //  5,177,344 B
    unsigned short* Ybf   = (unsigned short*)(ws + 15417344);  //  4,194,304 B

    transpose_wih<<<157 * 4, 256, 0, stream>>>(W_ih, W_ihT);
    prep_wout<<<NPAD, 256, 0, stream>>>(W_out, Wb);
    scan_kernel<<<BATCH, 512, 0, stream>>>(inputs, state, W_hh, b_ih, b_hh,
                                           W_ihT, Ybf, out + LOGITS_ELEMS);
    gemm_kernel<<<MTILES * NTILES, 256, 0, stream>>>(Ybf, Wb, b_out, out);
}